// Round 6
// baseline (133.957 us; speedup 1.0000x reference)
//
#include <hip/hip_runtime.h>

#define NN 32768
#define KK 32
#define DD 128

typedef float v2f __attribute__((ext_vector_type(2)));
typedef float v4f __attribute__((ext_vector_type(4)));

// ---------------------------------------------------------------------------
// Prep kernel: x8[r,:] = fp8_e4m3(x[r,:]) (128 B/row, per-branch table = 4 MiB)
//              xw[r]   = dot(x[r,:], w)   (fp32, exact op path)
// Block = 256 = 4 waves; wave handles 2 rows (32 lanes/row, 4 elems/lane).
// ---------------------------------------------------------------------------
__global__ __launch_bounds__(256) void prep_kernel(const float* __restrict__ x1,
                                                   const float* __restrict__ x2,
                                                   const float* __restrict__ w,
                                                   unsigned int* __restrict__ x8,
                                                   float* __restrict__ xw) {
    const int wave = threadIdx.x >> 6;
    const int lane = threadIdx.x & 63;
    const int half = lane >> 5;
    const int c    = lane & 31;
    const int row  = blockIdx.x * 8 + wave * 2 + half;   // 0..2N-1
    const float* x = (row < NN) ? (x1 + (size_t)row * DD)
                                : (x2 + (size_t)(row - NN) * DD);
    const float4 xv = *(const float4*)(x + 4 * c);
    const float4 wv = *(const float4*)(w + 4 * c);

    int packed = __builtin_amdgcn_cvt_pk_fp8_f32(xv.x, xv.y, 0, false);
    packed     = __builtin_amdgcn_cvt_pk_fp8_f32(xv.z, xv.w, packed, true);
    x8[(size_t)row * 32 + c] = (unsigned int)packed;

    float s = xv.x * wv.x + xv.y * wv.y + xv.z * wv.z + xv.w * wv.w;
    #pragma unroll
    for (int m = 16; m >= 1; m >>= 1)
        s += __shfl_xor(s, m, 64);            // reduce within each 32-half
    if (c == 0) xw[row] = s;
}

// ---------------------------------------------------------------------------
// Main kernel: 256 threads = 16 n-rows (16 lanes/row, 8 fp8-elems per lane via
// one uint2 gather). Branch chosen by XCD parity group so each XCD's L2 holds
// only ONE branch's 4 MiB table (assumes round-robin block->XCD; perf-only).
// All output stores nontemporal to avoid evicting the gather table from L2.
// ---------------------------------------------------------------------------
__global__ __launch_bounds__(256) void pgnn_main(
    const uint2* __restrict__ x8,   // [2N, 16] uint2 = 8 fp8 each
    const float* __restrict__ xw,   // [2N]
    const int* __restrict__ idx1, const float* __restrict__ dm1,
    const int* __restrict__ idx2, const float* __restrict__ dm2,
    const float* __restrict__ b_out,
    float* __restrict__ out)
{
    // grid.x = 2 * NN/16 = 4096. xcd = blockIdx%8; xcd 0-3 -> branch 0.
    const int g      = blockIdx.x;
    const int xcd    = g & 7;
    const int branch = xcd >> 2;
    const int nb     = (g >> 3) * 4 + (xcd & 3);     // [0, NN/16)

    const uint2* __restrict__ xb  = x8 + (size_t)branch * NN * 16;
    const float* __restrict__ xwb = xw + (size_t)branch * NN;
    const int*   __restrict__ idx = branch ? idx2 : idx1;
    const float* __restrict__ dm  = branch ? dm2  : dm1;
    float* __restrict__ op = out + (size_t)branch * ((size_t)NN * KK + (size_t)NN * DD);
    float* __restrict__ os = op + (size_t)NN * KK;

    __shared__ int   s_idx[16][KK + 1];   // +1 pad: sub-rows land in distinct banks
    __shared__ float s_dm [16][KK + 1];

    const int tid = threadIdx.x;
    const int n0  = nb * 16;

    // Stage idx/dm (16 rows x 32 k = 512 entries) and emit op on the way.
    const float bb = b_out[0];
    #pragma unroll
    for (int j = tid; j < 16 * KK; j += 256) {
        const int rr = j >> 5;
        const int k  = j & 31;
        const size_t off = (size_t)(n0 + rr) * KK + k;
        const int   i  = idx[off];
        const float dv = dm[off];
        s_idx[rr][k] = i;
        s_dm [rr][k] = dv;
        __builtin_nontemporal_store(dv * xwb[i] + bb, &op[off]);
    }
    __syncthreads();

    const int sub = tid >> 4;    // n-row within block: 0..15
    const int h   = tid & 15;    // 8-byte chunk within the 128 B row

    float a0=0.f,a1=0.f,a2=0.f,a3=0.f,a4=0.f,a5=0.f,a6=0.f,a7=0.f;
    #pragma unroll
    for (int k = 0; k < KK; ++k) {
        const int   r = s_idx[sub][k];
        const float d = s_dm [sub][k];
        const uint2 u = xb[(size_t)r * 16 + h];
        const v2f f0 = __builtin_amdgcn_cvt_pk_f32_fp8((int)u.x, false);
        const v2f f1 = __builtin_amdgcn_cvt_pk_f32_fp8((int)u.x, true);
        const v2f f2 = __builtin_amdgcn_cvt_pk_f32_fp8((int)u.y, false);
        const v2f f3 = __builtin_amdgcn_cvt_pk_f32_fp8((int)u.y, true);
        a0 += d * f0.x; a1 += d * f0.y; a2 += d * f1.x; a3 += d * f1.y;
        a4 += d * f2.x; a5 += d * f2.y; a6 += d * f3.x; a7 += d * f3.y;
    }
    const float inv = 1.0f / KK;
    v4f o0 = { a0 * inv, a1 * inv, a2 * inv, a3 * inv };
    v4f o1 = { a4 * inv, a5 * inv, a6 * inv, a7 * inv };
    float* dst = os + (size_t)(n0 + sub) * DD + h * 8;
    __builtin_nontemporal_store(o0, (v4f*)dst);
    __builtin_nontemporal_store(o1, (v4f*)(dst + 4));
}

// ---------------------------------------------------------------------------
// Fallback (ws too small): round-2 fused fp32 kernel, known-good at 124 us.
// ---------------------------------------------------------------------------
__global__ __launch_bounds__(256) void pgnn_fused(
    const float* __restrict__ x1, const int* __restrict__ idx1,
    const float* __restrict__ dm1,
    const float* __restrict__ x2, const int* __restrict__ idx2,
    const float* __restrict__ dm2,
    const float* __restrict__ w, const float* __restrict__ b_out,
    float* __restrict__ out)
{
    const int branch = blockIdx.y;
    const float* __restrict__ x   = branch ? x2   : x1;
    const int*   __restrict__ idx = branch ? idx2 : idx1;
    const float* __restrict__ dm  = branch ? dm2  : dm1;
    float* __restrict__ op = out + (size_t)branch * ((size_t)NN * KK + (size_t)NN * DD);
    float* __restrict__ os = op + (size_t)NN * KK;

    __shared__ int    s_idx[2][KK];
    __shared__ float  s_dm [2][KK];
    __shared__ float  s_dot[2][KK];
    __shared__ float4 s_acc[2][128];

    const int sub = threadIdx.x >> 7;
    const int t   = threadIdx.x & 127;
    const int gg  = t >> 5;
    const int c   = t & 31;
    const int n   = blockIdx.x * 2 + sub;

    if (t < KK) {
        s_idx[sub][t] = idx[(size_t)n * KK + t];
        s_dm [sub][t] = dm [(size_t)n * KK + t];
    }
    const float4 wv = *(const float4*)(w + 4 * c);
    __syncthreads();

    float4 acc = make_float4(0.f, 0.f, 0.f, 0.f);
    #pragma unroll
    for (int k0 = 0; k0 < KK / 4; ++k0) {
        const int   kk  = k0 * 4 + gg;
        const int   r   = s_idx[sub][kk];
        const float dmk = s_dm [sub][kk];
        const float4 v  = *(const float4*)(x + (size_t)r * DD + 4 * c);
        acc.x += dmk * v.x; acc.y += dmk * v.y;
        acc.z += dmk * v.z; acc.w += dmk * v.w;
        float p = v.x * wv.x + v.y * wv.y + v.z * wv.z + v.w * wv.w;
        #pragma unroll
        for (int m = 16; m >= 1; m >>= 1)
            p += __shfl_xor(p, m, 64);
        if (c == 0) s_dot[sub][kk] = p;
    }
    s_acc[sub][t] = acc;
    __syncthreads();

    if (t < KK)
        op[(size_t)n * KK + t] = s_dm[sub][t] * s_dot[sub][t] + b_out[0];
    if (t < 32) {
        const float4 b0 = s_acc[sub][t];
        const float4 b1 = s_acc[sub][32 + t];
        const float4 b2 = s_acc[sub][64 + t];
        const float4 b3 = s_acc[sub][96 + t];
        float4 r;
        r.x = (b0.x + b1.x + b2.x + b3.x) * (1.0f / KK);
        r.y = (b0.y + b1.y + b2.y + b3.y) * (1.0f / KK);
        r.z = (b0.z + b1.z + b2.z + b3.z) * (1.0f / KK);
        r.w = (b0.w + b1.w + b2.w + b3.w) * (1.0f / KK);
        *(float4*)(os + (size_t)n * DD + 4 * t) = r;
    }
}

extern "C" void kernel_launch(void* const* d_in, const int* in_sizes, int n_in,
                              void* d_out, int out_size, void* d_ws, size_t ws_size,
                              hipStream_t stream) {
    const float* x1   = (const float*)d_in[0];
    const int*   idx1 = (const int*)  d_in[1];
    const float* dm1  = (const float*)d_in[2];
    const float* x2   = (const float*)d_in[3];
    const int*   idx2 = (const int*)  d_in[4];
    const float* dm2  = (const float*)d_in[5];
    const float* w    = (const float*)d_in[6];
    const float* b    = (const float*)d_in[7];
    float* out = (float*)d_out;

    const size_t need = (size_t)2 * NN * DD                   // x8: 8.39 MB
                      + (size_t)2 * NN * sizeof(float);       // xw: 0.26 MB
    if (ws_size >= need) {
        unsigned int* x8 = (unsigned int*)d_ws;
        float*        xw = (float*)((char*)d_ws + (size_t)2 * NN * DD);
        prep_kernel<<<dim3(2 * NN / 8), dim3(256), 0, stream>>>(x1, x2, w, x8, xw);
        pgnn_main<<<dim3(2 * NN / 16), dim3(256), 0, stream>>>(
            (const uint2*)x8, xw, idx1, dm1, idx2, dm2, b, out);
    } else {
        pgnn_fused<<<dim3(NN / 2, 2), dim3(256), 0, stream>>>(
            x1, idx1, dm1, x2, idx2, dm2, w, b, out);
    }
}

// Round 7
// 132.214 us; speedup vs baseline: 1.0132x; 1.0132x over previous
//
#include <hip/hip_runtime.h>

#define NN 32768
#define KK 32
#define DD 128

typedef float v2f __attribute__((ext_vector_type(2)));
typedef float v4f __attribute__((ext_vector_type(4)));

// ---------------------------------------------------------------------------
// Prep kernel: x8[r,:] = fp8_e4m3(x[r,:]) (128 B/row, per-branch table = 4 MiB)
//              xw[r]   = dot(x[r,:], w)   (fp32, exact op path)
// Block = 256 = 4 waves; wave handles 2 rows (32 lanes/row, 4 elems/lane).
// ---------------------------------------------------------------------------
__global__ __launch_bounds__(256) void prep_kernel(const float* __restrict__ x1,
                                                   const float* __restrict__ x2,
                                                   const float* __restrict__ w,
                                                   unsigned int* __restrict__ x8,
                                                   float* __restrict__ xw) {
    const int wave = threadIdx.x >> 6;
    const int lane = threadIdx.x & 63;
    const int half = lane >> 5;
    const int c    = lane & 31;
    const int row  = blockIdx.x * 8 + wave * 2 + half;   // 0..2N-1
    const float* x = (row < NN) ? (x1 + (size_t)row * DD)
                                : (x2 + (size_t)(row - NN) * DD);
    const float4 xv = *(const float4*)(x + 4 * c);
    const float4 wv = *(const float4*)(w + 4 * c);

    int packed = __builtin_amdgcn_cvt_pk_fp8_f32(xv.x, xv.y, 0, false);
    packed     = __builtin_amdgcn_cvt_pk_fp8_f32(xv.z, xv.w, packed, true);
    x8[(size_t)row * 32 + c] = (unsigned int)packed;

    float s = xv.x * wv.x + xv.y * wv.y + xv.z * wv.z + xv.w * wv.w;
    #pragma unroll
    for (int m = 16; m >= 1; m >>= 1)
        s += __shfl_xor(s, m, 64);            // reduce within each 32-half
    if (c == 0) xw[row] = s;
}

// ---------------------------------------------------------------------------
// Main kernel: 256 threads = 16 n-rows (16 lanes/row, 8 fp8-elems per lane).
// k-loop is batched 8-deep with explicit register arrays so >=8 gathers are
// in flight per wave (round-6 version had VGPR=36 -> compiler serialized).
// (idx,dm) packed in one LDS uint2; stride KK+2 keeps 16B alignment and
// spreads the 4 sub-rows of a wave across distinct banks.
// ---------------------------------------------------------------------------
__global__ __launch_bounds__(256) void pgnn_main(
    const uint2* __restrict__ x8,   // [2N, 16] uint2 = 8 fp8 each
    const float* __restrict__ xw,   // [2N]
    const int* __restrict__ idx1, const float* __restrict__ dm1,
    const int* __restrict__ idx2, const float* __restrict__ dm2,
    const float* __restrict__ b_out,
    float* __restrict__ out)
{
    // grid.x = 2 * NN/16 = 4096. xcd = blockIdx%8; xcd 0-3 -> branch 0.
    const int g      = blockIdx.x;
    const int xcd    = g & 7;
    const int branch = xcd >> 2;
    const int nb     = (g >> 3) * 4 + (xcd & 3);     // [0, NN/16)

    const uint2* __restrict__ xb  = x8 + (size_t)branch * NN * 16;
    const float* __restrict__ xwb = xw + (size_t)branch * NN;
    const int*   __restrict__ idx = branch ? idx2 : idx1;
    const float* __restrict__ dm  = branch ? dm2  : dm1;
    float* __restrict__ op = out + (size_t)branch * ((size_t)NN * KK + (size_t)NN * DD);
    float* __restrict__ os = op + (size_t)NN * KK;

    __shared__ uint2 s_pair[16][KK + 2];  // .x = row idx, .y = dm bits

    const int tid = threadIdx.x;
    const int n0  = nb * 16;

    // Stage (idx,dm) for 16 rows x 32 k and emit op on the way.
    const float bb = b_out[0];
    #pragma unroll
    for (int j = tid; j < 16 * KK; j += 256) {
        const int rr = j >> 5;
        const int k  = j & 31;
        const size_t off = (size_t)(n0 + rr) * KK + k;
        const int   i  = idx[off];
        const float dv = dm[off];
        s_pair[rr][k] = make_uint2((unsigned)i, __float_as_uint(dv));
        __builtin_nontemporal_store(dv * xwb[i] + bb, &op[off]);
    }
    __syncthreads();

    const int sub = tid >> 4;    // n-row within block: 0..15
    const int h   = tid & 15;    // 8-byte chunk within the 128 B row
    const uint2* __restrict__ prow = s_pair[sub];

    float a0=0.f,a1=0.f,a2=0.f,a3=0.f,a4=0.f,a5=0.f,a6=0.f,a7=0.f;
    #pragma unroll
    for (int kb = 0; kb < KK; kb += 8) {
        uint2 pr[8];
        #pragma unroll
        for (int j = 0; j < 8; ++j) pr[j] = prow[kb + j];
        uint2 u[8];
        #pragma unroll
        for (int j = 0; j < 8; ++j)
            u[j] = xb[(size_t)pr[j].x * 16 + h];
        #pragma unroll
        for (int j = 0; j < 8; ++j) {
            const float d = __uint_as_float(pr[j].y);
            const v2f f0 = __builtin_amdgcn_cvt_pk_f32_fp8((int)u[j].x, false);
            const v2f f1 = __builtin_amdgcn_cvt_pk_f32_fp8((int)u[j].x, true);
            const v2f f2 = __builtin_amdgcn_cvt_pk_f32_fp8((int)u[j].y, false);
            const v2f f3 = __builtin_amdgcn_cvt_pk_f32_fp8((int)u[j].y, true);
            a0 += d * f0.x; a1 += d * f0.y; a2 += d * f1.x; a3 += d * f1.y;
            a4 += d * f2.x; a5 += d * f2.y; a6 += d * f3.x; a7 += d * f3.y;
        }
    }
    const float inv = 1.0f / KK;
    v4f o0 = { a0 * inv, a1 * inv, a2 * inv, a3 * inv };
    v4f o1 = { a4 * inv, a5 * inv, a6 * inv, a7 * inv };
    float* dst = os + (size_t)(n0 + sub) * DD + h * 8;
    __builtin_nontemporal_store(o0, (v4f*)dst);
    __builtin_nontemporal_store(o1, (v4f*)(dst + 4));
}

// ---------------------------------------------------------------------------
// Fallback (ws too small): round-2 fused fp32 kernel, known-good at 124 us.
// ---------------------------------------------------------------------------
__global__ __launch_bounds__(256) void pgnn_fused(
    const float* __restrict__ x1, const int* __restrict__ idx1,
    const float* __restrict__ dm1,
    const float* __restrict__ x2, const int* __restrict__ idx2,
    const float* __restrict__ dm2,
    const float* __restrict__ w, const float* __restrict__ b_out,
    float* __restrict__ out)
{
    const int branch = blockIdx.y;
    const float* __restrict__ x   = branch ? x2   : x1;
    const int*   __restrict__ idx = branch ? idx2 : idx1;
    const float* __restrict__ dm  = branch ? dm2  : dm1;
    float* __restrict__ op = out + (size_t)branch * ((size_t)NN * KK + (size_t)NN * DD);
    float* __restrict__ os = op + (size_t)NN * KK;

    __shared__ int    s_idx[2][KK];
    __shared__ float  s_dm [2][KK];
    __shared__ float  s_dot[2][KK];
    __shared__ float4 s_acc[2][128];

    const int sub = threadIdx.x >> 7;
    const int t   = threadIdx.x & 127;
    const int gg  = t >> 5;
    const int c   = t & 31;
    const int n   = blockIdx.x * 2 + sub;

    if (t < KK) {
        s_idx[sub][t] = idx[(size_t)n * KK + t];
        s_dm [sub][t] = dm [(size_t)n * KK + t];
    }
    const float4 wv = *(const float4*)(w + 4 * c);
    __syncthreads();

    float4 acc = make_float4(0.f, 0.f, 0.f, 0.f);
    #pragma unroll
    for (int k0 = 0; k0 < KK / 4; ++k0) {
        const int   kk  = k0 * 4 + gg;
        const int   r   = s_idx[sub][kk];
        const float dmk = s_dm [sub][kk];
        const float4 v  = *(const float4*)(x + (size_t)r * DD + 4 * c);
        acc.x += dmk * v.x; acc.y += dmk * v.y;
        acc.z += dmk * v.z; acc.w += dmk * v.w;
        float p = v.x * wv.x + v.y * wv.y + v.z * wv.z + v.w * wv.w;
        #pragma unroll
        for (int m = 16; m >= 1; m >>= 1)
            p += __shfl_xor(p, m, 64);
        if (c == 0) s_dot[sub][kk] = p;
    }
    s_acc[sub][t] = acc;
    __syncthreads();

    if (t < KK)
        op[(size_t)n * KK + t] = s_dm[sub][t] * s_dot[sub][t] + b_out[0];
    if (t < 32) {
        const float4 b0 = s_acc[sub][t];
        const float4 b1 = s_acc[sub][32 + t];
        const float4 b2 = s_acc[sub][64 + t];
        const float4 b3 = s_acc[sub][96 + t];
        float4 r;
        r.x = (b0.x + b1.x + b2.x + b3.x) * (1.0f / KK);
        r.y = (b0.y + b1.y + b2.y + b3.y) * (1.0f / KK);
        r.z = (b0.z + b1.z + b2.z + b3.z) * (1.0f / KK);
        r.w = (b0.w + b1.w + b2.w + b3.w) * (1.0f / KK);
        *(float4*)(os + (size_t)n * DD + 4 * t) = r;
    }
}

extern "C" void kernel_launch(void* const* d_in, const int* in_sizes, int n_in,
                              void* d_out, int out_size, void* d_ws, size_t ws_size,
                              hipStream_t stream) {
    const float* x1   = (const float*)d_in[0];
    const int*   idx1 = (const int*)  d_in[1];
    const float* dm1  = (const float*)d_in[2];
    const float* x2   = (const float*)d_in[3];
    const int*   idx2 = (const int*)  d_in[4];
    const float* dm2  = (const float*)d_in[5];
    const float* w    = (const float*)d_in[6];
    const float* b    = (const float*)d_in[7];
    float* out = (float*)d_out;

    const size_t need = (size_t)2 * NN * DD                   // x8: 8.39 MB
                      + (size_t)2 * NN * sizeof(float);       // xw: 0.26 MB
    if (ws_size >= need) {
        unsigned int* x8 = (unsigned int*)d_ws;
        float*        xw = (float*)((char*)d_ws + (size_t)2 * NN * DD);
        prep_kernel<<<dim3(2 * NN / 8), dim3(256), 0, stream>>>(x1, x2, w, x8, xw);
        pgnn_main<<<dim3(2 * NN / 16), dim3(256), 0, stream>>>(
            (const uint2*)x8, xw, idx1, dm1, idx2, dm2, b, out);
    } else {
        pgnn_fused<<<dim3(NN / 2, 2), dim3(256), 0, stream>>>(
            x1, idx1, dm1, x2, idx2, dm2, w, b, out);
    }
}